// Round 5
// baseline (2670.972 us; speedup 1.0000x reference)
//
#include <hip/hip_runtime.h>

#define NBANK 64
#define ACC_STRIDE (NBANK * 128) // floats per stage accumulator region

// ---------------- init kernels ----------------
__global__ void init_zero_kernel(float* __restrict__ p, int n) {
    int i = blockIdx.x * 256 + threadIdx.x;
    if (i < n) p[i] = 0.f;
}
__global__ void init_m1_kernel(int* __restrict__ p, int n) {
    int i = blockIdx.x * 256 + threadIdx.x;
    if (i < n) p[i] = -1;
}

// ---------------- gather-conv ----------------
// out[m, c] = sum_k (nbr[m,k]>=0) * feats[nbr[m,k]] @ W[k]
// 256 threads; each thread computes CPT=4 output channels for one row.
template <int CIN, int COUT, int K, bool DUAL>
__global__ __launch_bounds__(256) void gconv_kernel(
    const float* __restrict__ feats, const int* __restrict__ nbr,
    const float* __restrict__ W1, const float* __restrict__ W2,
    float* __restrict__ out1, float* __restrict__ out2, int M)
{
    constexpr int CPT  = 4;
    constexpr int TPR  = COUT / CPT;   // threads per row
    constexpr int ROWS = 256 / TPR;    // rows per block
    constexpr int LDF  = CIN + 8;      // padded row stride (16B-aligned, breaks bank aliasing)
    __shared__ float shf[ROWS * LDF];
    __shared__ int   shn[ROWS * K];

    const int tid = threadIdx.x;
    const int tr  = tid % TPR;
    const int r   = tid / TPR;
    const int m0  = blockIdx.x * ROWS;
    const int m   = m0 + r;

    // stage neighbor indices for the block's rows
    for (int i = tid; i < ROWS * K; i += 256) {
        int row = i / K;
        int kk  = i - row * K;
        int gm  = m0 + row;
        shn[i] = (gm < M) ? nbr[(size_t)gm * K + kk] : -1;
    }

    float4 a1 = make_float4(0.f, 0.f, 0.f, 0.f);
    float4 a2 = make_float4(0.f, 0.f, 0.f, 0.f);
    const int c0 = tr * CPT;
    float* shr = shf + r * LDF;

    for (int k = 0; k < K; ++k) {
        __syncthreads(); // covers shn writes (iter 0) and prev-iter MAC reads of shf
        const int idx = shn[r * K + k];
        // stage gathered feature row (zeros if invalid; MAC skipped anyway)
        for (int j = tr; j < CIN / 4; j += TPR) {
            float4 vv = make_float4(0.f, 0.f, 0.f, 0.f);
            if (idx >= 0) vv = ((const float4*)(feats + (size_t)idx * CIN))[j];
            ((float4*)shr)[j] = vv;
        }
        __syncthreads();
        if (idx >= 0) {
            const float* w1 = W1 + (size_t)k * CIN * COUT + c0;
            #pragma unroll 4
            for (int q = 0; q < CIN / 4; ++q) {
                float4 f = ((const float4*)shr)[q];
                const float* wp = w1 + q * 4 * COUT;
                float4 wa = *(const float4*)(wp);
                float4 wb = *(const float4*)(wp + COUT);
                float4 wc = *(const float4*)(wp + 2 * COUT);
                float4 wd = *(const float4*)(wp + 3 * COUT);
                a1.x += f.x * wa.x; a1.y += f.x * wa.y; a1.z += f.x * wa.z; a1.w += f.x * wa.w;
                a1.x += f.y * wb.x; a1.y += f.y * wb.y; a1.z += f.y * wb.z; a1.w += f.y * wb.w;
                a1.x += f.z * wc.x; a1.y += f.z * wc.y; a1.z += f.z * wc.z; a1.w += f.z * wc.w;
                a1.x += f.w * wd.x; a1.y += f.w * wd.y; a1.z += f.w * wd.z; a1.w += f.w * wd.w;
                if constexpr (DUAL) {
                    const float* wp2 = W2 + (size_t)k * CIN * COUT + c0 + q * 4 * COUT;
                    float4 va = *(const float4*)(wp2);
                    float4 vb = *(const float4*)(wp2 + COUT);
                    float4 vc = *(const float4*)(wp2 + 2 * COUT);
                    float4 vd = *(const float4*)(wp2 + 3 * COUT);
                    a2.x += f.x * va.x; a2.y += f.x * va.y; a2.z += f.x * va.z; a2.w += f.x * va.w;
                    a2.x += f.y * vb.x; a2.y += f.y * vb.y; a2.z += f.y * vb.z; a2.w += f.y * vb.w;
                    a2.x += f.z * vc.x; a2.y += f.z * vc.y; a2.z += f.z * vc.z; a2.w += f.z * vc.w;
                    a2.x += f.w * vd.x; a2.y += f.w * vd.y; a2.z += f.w * vd.z; a2.w += f.w * vd.w;
                }
            }
        }
    }
    if (m < M) {
        *((float4*)(out1 + (size_t)m * COUT + c0)) = a1;
        if constexpr (DUAL) *((float4*)(out2 + (size_t)m * COUT + c0)) = a2;
    }
}

// ---------------- BN stats (sum / sumsq per channel, banked atomics) ----------------
template <int C>
__global__ __launch_bounds__(256) void stats_kernel(
    const float* __restrict__ x, int M, float* __restrict__ acc)
{
    constexpr int RPB = 256 / C;
    const int c = threadIdx.x % C;
    const int r = threadIdx.x / C;
    float s = 0.f, s2 = 0.f;
    for (long m = (long)blockIdx.x * RPB + r; m < M; m += (long)gridDim.x * RPB) {
        float v = x[m * C + c];
        s += v;
        s2 += v * v;
    }
    __shared__ float sh[2][256];
    sh[0][threadIdx.x] = s;
    sh[1][threadIdx.x] = s2;
    __syncthreads();
    if (r == 0) {
        #pragma unroll
        for (int j = 1; j < RPB; ++j) {
            s  += sh[0][j * C + c];
            s2 += sh[1][j * C + c];
        }
        float* a = acc + (blockIdx.x % NBANK) * 128;
        atomicAdd(&a[c], s);
        atomicAdd(&a[64 + c], s2);
    }
}

template <int C>
__global__ void finalize_kernel(const float* __restrict__ acc, const float* __restrict__ g,
                                const float* __restrict__ b, int M, float* __restrict__ sc)
{
    int c = threadIdx.x;
    if (c < C) {
        float s = 0.f, s2 = 0.f;
        for (int k = 0; k < NBANK; ++k) {
            s  += acc[k * 128 + c];
            s2 += acc[k * 128 + 64 + c];
        }
        float inv  = 1.f / (float)M;
        float mean = s * inv;
        float var  = s2 * inv - mean * mean;
        float rstd = rsqrtf(var + 1e-3f);
        float scale = g[c] * rstd;
        sc[c]      = scale;
        sc[64 + c] = b[c] - mean * scale;
    }
}

// ---------------- elementwise ----------------
__global__ void apply_kernel(const float* __restrict__ x, const float* __restrict__ sc,
                             const float* __restrict__ addv, float* __restrict__ out,
                             long total, int cmask, int relu)
{
    long i = (long)blockIdx.x * 256 + threadIdx.x;
    if (i >= total) return;
    int c = (int)(i & cmask);
    float v = x[i] * sc[c] + sc[64 + c];
    if (relu) v = fmaxf(v, 0.f);
    if (addv) v += addv[i];
    out[i] = v;
}

__global__ void add_kernel(float* __restrict__ a, const float* __restrict__ b, long total)
{
    long i = (long)blockIdx.x * 256 + threadIdx.x;
    if (i < total) a[i] += b[i];
}

// ---------------- 2D projection / grid / neighbors ----------------
// Round-5 precision model: the np reference runs the pipeline with inputs
// upcast to float64 BUT preserves the explicit `fi = down.astype(float32)`.
// numpy then gives: x/y/z in f32 (f32 array * weak python scalar stays f32;
// scalar constants cast to f32; one mul + one add rounding each), while both
// einsums and the division promote to f64 (f32 pts vs f64 calib). The f64
// part is order/FMA-insensitive (~1e-16), so ALL bucket-boundary sensitivity
// is in the unambiguous f32 x/y/z rounding. Prior rounds eliminated:
// full-f32-noFMA (R2), full-f64 (R3), full-f32-FMA (R4) — R3==R4 output
// showed flips only matter when they change a grid-cell argmax winner.
__global__ void uv_kernel(const int* __restrict__ down, const float* __restrict__ l2r,
                          const float* __restrict__ p2, int M,
                          int* __restrict__ ub, int* __restrict__ vb)
{
    int m = blockIdx.x * 256 + threadIdx.x;
    if (m >= M) return;
    int b = down[4 * m];
    float fz = (float)down[4 * m + 1];
    float fy = (float)down[4 * m + 2];
    float fx = (float)down[4 * m + 3];
    // f32 stage (matches numpy: f32 array op weak scalar -> f32, two roundings)
    const float vs = 0.4f; // f32(0.05*8)
    float x = __fadd_rn(__fmul_rn(fx, vs), 0.2f);
    float y = __fadd_rn(__fmul_rn(fy, vs), -39.79999923706054688f); // f32(-40.0+0.2)
    float z = __fadd_rn(__fmul_rn(fz, vs), -2.79999995231628418f);  // f32(-3.0+0.2)
    // f64 stage (einsum promotes f32 pts against f64-upcast calib)
    double xd = (double)x, yd = (double)y, zd = (double)z;
    const float* L = l2r + b * 12;
    double r0 = (double)L[0] * xd + (double)L[1] * yd + (double)L[2]  * zd + (double)L[3];
    double r1 = (double)L[4] * xd + (double)L[5] * yd + (double)L[6]  * zd + (double)L[7];
    double r2 = (double)L[8] * xd + (double)L[9] * yd + (double)L[10] * zd + (double)L[11];
    const float* P = p2 + b * 12;
    double p0 = (double)P[0] * r0 + (double)P[1] * r1 + (double)P[2]  * r2 + (double)P[3];
    double p1 = (double)P[4] * r0 + (double)P[5] * r1 + (double)P[6]  * r2 + (double)P[7];
    double pz = (double)P[8] * r0 + (double)P[9] * r1 + (double)P[10] * r2 + (double)P[11];
    int u = (int)(p0 / pz); // f64 divide, trunc toward zero = astype(int32)
    int v = (int)(p1 / pz);
    u = min(max(u, 0), 1392) >> 3; // clip(0, 1400-8) // 8
    v = min(max(v, 0), 392) >> 3;  // clip(0, 400-8) // 8
    ub[m] = u;
    vb[m] = v;
}

__global__ void scatter_kernel(const int* __restrict__ down, const int* __restrict__ ub,
                               const int* __restrict__ vb, int* __restrict__ grid, int M)
{
    int m = blockIdx.x * 256 + threadIdx.x;
    if (m >= M) return;
    int b = down[4 * m];
    atomicMax(&grid[(b * 175 + ub[m]) * 50 + vb[m]], m);
}

__global__ void nbr2d_kernel(const int* __restrict__ down, const int* __restrict__ ub,
                             const int* __restrict__ vb, const int* __restrict__ grid,
                             int* __restrict__ nb2, int M)
{
    int m = blockIdx.x * 256 + threadIdx.x;
    if (m >= M) return;
    int b = down[4 * m];
    int u = ub[m], v = vb[m];
    #pragma unroll
    for (int j = 0; j < 9; ++j) {
        int uu = u + j / 3 - 1;
        int vv = v + j % 3 - 1;
        int val = -1;
        if (uu >= 0 && uu < 175 && vv >= 0 && vv < 50) val = grid[(b * 175 + uu) * 50 + vv];
        nb2[m * 9 + j] = val;
    }
}

// ---------------- orchestration ----------------
extern "C" void kernel_launch(void* const* d_in, const int* in_sizes, int n_in,
                              void* d_out, int out_size, void* d_ws, size_t ws_size,
                              hipStream_t stream)
{
    const float* feats  = (const float*)d_in[0];
    const float* Wd1    = (const float*)d_in[1];
    const float* Wres   = (const float*)d_in[2];
    const float* Wsub2  = (const float*)d_in[3];
    const float* W2d1   = (const float*)d_in[4];
    const float* W2d2   = (const float*)d_in[5];
    const float* Wsub3  = (const float*)d_in[6];
    const float* Winv4  = (const float*)d_in[7];
    const float* bn32g  = (const float*)d_in[8];
    const float* bn32b  = (const float*)d_in[9];
    const float* bn64g  = (const float*)d_in[10];
    const float* bn64b  = (const float*)d_in[11];
    const float* l2r    = (const float*)d_in[12];
    const float* p2c    = (const float*)d_in[13];
    const int*   down   = (const int*)d_in[14];
    const int*   nbrD   = (const int*)d_in[15];
    const int*   nbrS   = (const int*)d_in[16];
    const int*   nbrI   = (const int*)d_in[17];

    const int N = in_sizes[0] / 64;
    const int M = in_sizes[14] / 4;

    char* ws = (char*)d_ws;
    size_t off = 0;
    auto alloc = [&](size_t bytes) -> void* {
        void* p = ws + off;
        off = (off + bytes + 255) & ~(size_t)255;
        return p;
    };
    float* t0   = (float*)alloc((size_t)M * 32 * 4);
    float* t1   = (float*)alloc((size_t)M * 32 * 4);
    float* t2   = (float*)alloc((size_t)M * 32 * 4);
    int*   ub   = (int*)alloc((size_t)M * 4);
    int*   vb   = (int*)alloc((size_t)M * 4);
    int*   nb2  = (int*)alloc((size_t)M * 9 * 4);
    int*   grid = (int*)alloc((size_t)2 * 175 * 50 * 4);
    float* acc  = (float*)alloc((size_t)9 * ACC_STRIDE * 4);
    float* sc   = (float*)alloc((size_t)9 * 128 * 4);
    float* g0   = (float*)d_out; // N*64 stream computed in the output buffer

    const int accN = 9 * ACC_STRIDE;
    init_zero_kernel<<<(accN + 255) / 256, 256, 0, stream>>>(acc, accN);
    init_m1_kernel<<<(17500 + 255) / 256, 256, 0, stream>>>(grid, 17500);

    const int  gM32  = (M + 31) / 32;          // COUT=32 convs: 32 rows/block
    const long tot32 = (long)M * 32;
    const int  gA    = (int)((tot32 + 255) / 256);
    const int  gM    = (M + 255) / 256;

    // stage 1: down1 + res share gathers
    gconv_kernel<64, 32, 27, true><<<gM32, 256, 0, stream>>>(feats, nbrD, Wd1, Wres, t0, t1, M);
    stats_kernel<32><<<256, 256, 0, stream>>>(t0, M, acc + 0 * ACC_STRIDE);
    stats_kernel<32><<<256, 256, 0, stream>>>(t1, M, acc + 1 * ACC_STRIDE);
    finalize_kernel<32><<<1, 64, 0, stream>>>(acc + 0 * ACC_STRIDE, bn32g + 0 * 32, bn32b + 0 * 32, M, sc + 0 * 128);
    finalize_kernel<32><<<1, 64, 0, stream>>>(acc + 1 * ACC_STRIDE, bn32g + 2 * 32, bn32b + 2 * 32, M, sc + 1 * 128);
    apply_kernel<<<gA, 256, 0, stream>>>(t0, sc + 0 * 128, nullptr, t0, tot32, 31, 1); // d3a
    apply_kernel<<<gA, 256, 0, stream>>>(t1, sc + 1 * 128, nullptr, t1, tot32, 31, 1); // res

    // stage 2: sub2, then d3 = relu(bn(conv)) + res
    gconv_kernel<32, 32, 27, false><<<gM32, 256, 0, stream>>>(t0, nbrS, Wsub2, nullptr, t2, nullptr, M);
    stats_kernel<32><<<256, 256, 0, stream>>>(t2, M, acc + 2 * ACC_STRIDE);
    finalize_kernel<32><<<1, 64, 0, stream>>>(acc + 2 * ACC_STRIDE, bn32g + 1 * 32, bn32b + 1 * 32, M, sc + 2 * 128);
    apply_kernel<<<gA, 256, 0, stream>>>(t2, sc + 2 * 128, t1, t2, tot32, 31, 1); // t2 = d3

    // 2D neighbor construction
    uv_kernel<<<gM, 256, 0, stream>>>(down, l2r, p2c, M, ub, vb);
    scatter_kernel<<<gM, 256, 0, stream>>>(down, ub, vb, grid, M);
    nbr2d_kernel<<<gM, 256, 0, stream>>>(down, ub, vb, grid, nb2, M);

    // 2d conv 1
    gconv_kernel<32, 32, 9, false><<<gM32, 256, 0, stream>>>(t2, nb2, W2d1, nullptr, t0, nullptr, M);
    stats_kernel<32><<<256, 256, 0, stream>>>(t0, M, acc + 3 * ACC_STRIDE);
    finalize_kernel<32><<<1, 64, 0, stream>>>(acc + 3 * ACC_STRIDE, bn32g + 3 * 32, bn32b + 3 * 32, M, sc + 3 * 128);
    apply_kernel<<<gA, 256, 0, stream>>>(t0, sc + 3 * 128, nullptr, t0, tot32, 31, 1); // d2a

    // 2d conv 2
    gconv_kernel<32, 32, 9, false><<<gM32, 256, 0, stream>>>(t0, nb2, W2d2, nullptr, t1, nullptr, M);
    stats_kernel<32><<<256, 256, 0, stream>>>(t1, M, acc + 4 * ACC_STRIDE);
    finalize_kernel<32><<<1, 64, 0, stream>>>(acc + 4 * ACC_STRIDE, bn32g + 4 * 32, bn32b + 4 * 32, M, sc + 4 * 128);
    apply_kernel<<<gA, 256, 0, stream>>>(t1, sc + 4 * 128, nullptr, t1, tot32, 31, 1); // d2b

    // d3 = bn(d3 + d2)
    add_kernel<<<gA, 256, 0, stream>>>(t1, t2, tot32);
    stats_kernel<32><<<256, 256, 0, stream>>>(t1, M, acc + 5 * ACC_STRIDE);
    finalize_kernel<32><<<1, 64, 0, stream>>>(acc + 5 * ACC_STRIDE, bn32g + 5 * 32, bn32b + 5 * 32, M, sc + 5 * 128);
    apply_kernel<<<gA, 256, 0, stream>>>(t1, sc + 5 * 128, nullptr, t1, tot32, 31, 0);

    // sub3
    gconv_kernel<32, 32, 27, false><<<gM32, 256, 0, stream>>>(t1, nbrS, Wsub3, nullptr, t0, nullptr, M);
    stats_kernel<32><<<256, 256, 0, stream>>>(t0, M, acc + 6 * ACC_STRIDE);
    finalize_kernel<32><<<1, 64, 0, stream>>>(acc + 6 * ACC_STRIDE, bn32g + 6 * 32, bn32b + 6 * 32, M, sc + 6 * 128);
    apply_kernel<<<gA, 256, 0, stream>>>(t0, sc + 6 * 128, nullptr, t0, tot32, 31, 1); // d3f

    // inv4 (N rows) -> directly into d_out
    const int  gN16  = (N + 15) / 16;          // COUT=64 conv: 16 rows/block
    const long tot64 = (long)N * 64;
    const int  gB    = (int)((tot64 + 255) / 256);
    gconv_kernel<32, 64, 27, false><<<gN16, 256, 0, stream>>>(t0, nbrI, Winv4, nullptr, g0, nullptr, N);
    stats_kernel<64><<<512, 256, 0, stream>>>(g0, N, acc + 7 * ACC_STRIDE);
    finalize_kernel<64><<<1, 64, 0, stream>>>(acc + 7 * ACC_STRIDE, bn64g + 0 * 64, bn64b + 0 * 64, N, sc + 7 * 128);
    apply_kernel<<<gB, 256, 0, stream>>>(g0, sc + 7 * 128, nullptr, g0, tot64, 63, 1); // out2

    // final: bn(out2 + features) -> d_out (in place)
    add_kernel<<<gB, 256, 0, stream>>>(g0, feats, tot64);
    stats_kernel<64><<<512, 256, 0, stream>>>(g0, N, acc + 8 * ACC_STRIDE);
    finalize_kernel<64><<<1, 64, 0, stream>>>(acc + 8 * ACC_STRIDE, bn64g + 1 * 64, bn64b + 1 * 64, N, sc + 8 * 128);
    apply_kernel<<<gB, 256, 0, stream>>>(g0, sc + 8 * 128, nullptr, (float*)d_out, tot64, 63, 0);
}

// Round 6
// 2001.732 us; speedup vs baseline: 1.3343x; 1.3343x over previous
//
#include <hip/hip_runtime.h>

#define NBANK 64
#define ACC_STRIDE (NBANK * 128) // floats per stage accumulator region

// ---------------- init kernels ----------------
__global__ void init_zero_kernel(float* __restrict__ p, int n) {
    int i = blockIdx.x * 256 + threadIdx.x;
    if (i < n) p[i] = 0.f;
}
__global__ void init_m1_kernel(int* __restrict__ p, int n) {
    int i = blockIdx.x * 256 + threadIdx.x;
    if (i < n) p[i] = -1;
}

// ---------------- gather-conv, wave-column GEMM form ----------------
// out[m,c] = sum_k sum_ci feats[nbr[m,k]][ci] * W[k][ci][c]
// Block: 256 threads = 4 waves, 64 output rows (row = lane).
// Each wave owns a wave-uniform column slice [wv*CPW, wv*CPW+CPW) ->
// weight addresses are wave-uniform => scalar (s_load) on the constant pipe,
// broadcast to all lanes as FMA operands. Features staged TRANSPOSED in LDS
// (shT[ci][row]: lane-stride-1, conflict-free) and software-pipelined:
// issue k+1 gather loads -> compute k -> ds_write k+1 (vmcnt drains after FMAs).
template <int CIN, int COUT, int K, bool DUAL>
__global__ __launch_bounds__(256) void gconv2_kernel(
    const float* __restrict__ feats, const int* __restrict__ nbr,
    const float* __restrict__ W1, const float* __restrict__ W2,
    float* __restrict__ out1, float* __restrict__ out2, int M)
{
    constexpr int CPW = COUT / 4;   // cols per wave: 8 (COUT=32) or 16 (COUT=64)
    constexpr int FPT = CIN / 4;    // floats staged per thread per row-chunk
    constexpr int NV  = FPT / 4;    // float4s staged per thread

    __shared__ float shT[2][CIN][64];
    __shared__ int   shn[K][64];

    const int tid  = threadIdx.x;
    const int lane = tid & 63;
    const int g    = tid >> 6;                                   // staging ci-group (VGPR)
    const int wv   = __builtin_amdgcn_readfirstlane(tid >> 6);   // wave id (SGPR)
    const int m0   = blockIdx.x * 64;

    // stage neighbor indices [k][row]
    for (int i = tid; i < K * 64; i += 256) {
        int kk = i >> 6, rr = i & 63;
        int gm = m0 + rr;
        shn[kk][rr] = (gm < M) ? nbr[(size_t)gm * K + kk] : -1;
    }

    float acc1[CPW];
    float acc2[DUAL ? CPW : 1];
    #pragma unroll
    for (int j = 0; j < CPW; ++j) acc1[j] = 0.f;
    if constexpr (DUAL) {
        #pragma unroll
        for (int j = 0; j < CPW; ++j) acc2[j] = 0.f;
    }

    __syncthreads(); // shn visible

    // prologue: stage k=0 into buffer 0
    {
        int idx = shn[0][lane];
        const float4* src = (const float4*)(feats + (size_t)max(idx, 0) * CIN) + g * NV;
        float4 v[NV];
        #pragma unroll
        for (int q = 0; q < NV; ++q) v[q] = src[q];
        #pragma unroll
        for (int q = 0; q < NV; ++q) {
            if (idx < 0) v[q] = make_float4(0.f, 0.f, 0.f, 0.f);
            int cb = g * FPT + q * 4;
            shT[0][cb + 0][lane] = v[q].x;
            shT[0][cb + 1][lane] = v[q].y;
            shT[0][cb + 2][lane] = v[q].z;
            shT[0][cb + 3][lane] = v[q].w;
        }
    }
    __syncthreads();

    const float* W1w = W1 + wv * CPW;
    const float* W2w = DUAL ? (W2 + wv * CPW) : nullptr;

    for (int k = 0; k < K; ++k) {
        const int b = k & 1;

        // issue next tile's gather loads (results consumed after compute)
        float4 v[NV];
        int nidx = -1;
        if (k + 1 < K) {
            nidx = shn[k + 1][lane];
            const float4* src = (const float4*)(feats + (size_t)max(nidx, 0) * CIN) + g * NV;
            #pragma unroll
            for (int q = 0; q < NV; ++q) v[q] = src[q];
        }

        // compute on buffer b; weights via wave-uniform scalar loads
        const float* Wk1 = W1w + (size_t)k * CIN * COUT;
        #pragma unroll 2
        for (int ci = 0; ci < CIN; ++ci) {
            float f = shT[b][ci][lane];
            const float* w1 = Wk1 + ci * COUT;
            #pragma unroll
            for (int j = 0; j < CPW; ++j) acc1[j] = fmaf(f, w1[j], acc1[j]);
            if constexpr (DUAL) {
                const float* w2 = W2w + (size_t)k * CIN * COUT + ci * COUT;
                #pragma unroll
                for (int j = 0; j < CPW; ++j) acc2[j] = fmaf(f, w2[j], acc2[j]);
            }
        }

        // write next tile (vmcnt drain lands here, after the FMAs)
        if (k + 1 < K) {
            #pragma unroll
            for (int q = 0; q < NV; ++q) {
                if (nidx < 0) v[q] = make_float4(0.f, 0.f, 0.f, 0.f);
                int cb = g * FPT + q * 4;
                shT[b ^ 1][cb + 0][lane] = v[q].x;
                shT[b ^ 1][cb + 1][lane] = v[q].y;
                shT[b ^ 1][cb + 2][lane] = v[q].z;
                shT[b ^ 1][cb + 3][lane] = v[q].w;
            }
        }
        __syncthreads();
    }

    const int m = m0 + lane;
    if (m < M) {
        float4* d1 = (float4*)(out1 + (size_t)m * COUT + wv * CPW);
        #pragma unroll
        for (int q = 0; q < CPW / 4; ++q)
            d1[q] = make_float4(acc1[q * 4], acc1[q * 4 + 1], acc1[q * 4 + 2], acc1[q * 4 + 3]);
        if constexpr (DUAL) {
            float4* d2 = (float4*)(out2 + (size_t)m * COUT + wv * CPW);
            #pragma unroll
            for (int q = 0; q < CPW / 4; ++q)
                d2[q] = make_float4(acc2[q * 4], acc2[q * 4 + 1], acc2[q * 4 + 2], acc2[q * 4 + 3]);
        }
    }
}

// ---------------- BN stats (sum / sumsq per channel, banked atomics) ----------------
template <int C>
__global__ __launch_bounds__(256) void stats_kernel(
    const float* __restrict__ x, int M, float* __restrict__ acc)
{
    constexpr int RPB = 256 / C;
    const int c = threadIdx.x % C;
    const int r = threadIdx.x / C;
    float s = 0.f, s2 = 0.f;
    for (long m = (long)blockIdx.x * RPB + r; m < M; m += (long)gridDim.x * RPB) {
        float v = x[m * C + c];
        s += v;
        s2 += v * v;
    }
    __shared__ float sh[2][256];
    sh[0][threadIdx.x] = s;
    sh[1][threadIdx.x] = s2;
    __syncthreads();
    if (r == 0) {
        #pragma unroll
        for (int j = 1; j < RPB; ++j) {
            s  += sh[0][j * C + c];
            s2 += sh[1][j * C + c];
        }
        float* a = acc + (blockIdx.x % NBANK) * 128;
        atomicAdd(&a[c], s);
        atomicAdd(&a[64 + c], s2);
    }
}

template <int C>
__global__ void finalize_kernel(const float* __restrict__ acc, const float* __restrict__ g,
                                const float* __restrict__ b, int M, float* __restrict__ sc)
{
    int c = threadIdx.x;
    if (c < C) {
        float s = 0.f, s2 = 0.f;
        for (int k = 0; k < NBANK; ++k) {
            s  += acc[k * 128 + c];
            s2 += acc[k * 128 + 64 + c];
        }
        float inv  = 1.f / (float)M;
        float mean = s * inv;
        float var  = s2 * inv - mean * mean;
        float rstd = rsqrtf(var + 1e-3f);
        float scale = g[c] * rstd;
        sc[c]      = scale;
        sc[64 + c] = b[c] - mean * scale;
    }
}

// ---------------- elementwise ----------------
__global__ void apply_kernel(const float* __restrict__ x, const float* __restrict__ sc,
                             const float* __restrict__ addv, float* __restrict__ out,
                             long total, int cmask, int relu)
{
    long i = (long)blockIdx.x * 256 + threadIdx.x;
    if (i >= total) return;
    int c = (int)(i & cmask);
    float v = x[i] * sc[c] + sc[64 + c];
    if (relu) v = fmaxf(v, 0.f);
    if (addv) v += addv[i];
    out[i] = v;
}

__global__ void add_kernel(float* __restrict__ a, const float* __restrict__ b, long total)
{
    long i = (long)blockIdx.x * 256 + threadIdx.x;
    if (i < total) a[i] += b[i];
}

// ---------------- 2D projection / grid / neighbors ----------------
// Verified precision model (R5 PASS): x/y/z in f32 (numpy weak-scalar ops on
// the f32-cast indices), einsums + division in f64 (f32 pts promoted against
// f64-upcast calib). Do not change.
__global__ void uv_kernel(const int* __restrict__ down, const float* __restrict__ l2r,
                          const float* __restrict__ p2, int M,
                          int* __restrict__ ub, int* __restrict__ vb)
{
    int m = blockIdx.x * 256 + threadIdx.x;
    if (m >= M) return;
    int b = down[4 * m];
    float fz = (float)down[4 * m + 1];
    float fy = (float)down[4 * m + 2];
    float fx = (float)down[4 * m + 3];
    const float vs = 0.4f; // f32(0.05*8)
    float x = __fadd_rn(__fmul_rn(fx, vs), 0.2f);
    float y = __fadd_rn(__fmul_rn(fy, vs), -39.79999923706054688f); // f32(-40.0+0.2)
    float z = __fadd_rn(__fmul_rn(fz, vs), -2.79999995231628418f);  // f32(-3.0+0.2)
    double xd = (double)x, yd = (double)y, zd = (double)z;
    const float* L = l2r + b * 12;
    double r0 = (double)L[0] * xd + (double)L[1] * yd + (double)L[2]  * zd + (double)L[3];
    double r1 = (double)L[4] * xd + (double)L[5] * yd + (double)L[6]  * zd + (double)L[7];
    double r2 = (double)L[8] * xd + (double)L[9] * yd + (double)L[10] * zd + (double)L[11];
    const float* P = p2 + b * 12;
    double p0 = (double)P[0] * r0 + (double)P[1] * r1 + (double)P[2]  * r2 + (double)P[3];
    double p1 = (double)P[4] * r0 + (double)P[5] * r1 + (double)P[6]  * r2 + (double)P[7];
    double pz = (double)P[8] * r0 + (double)P[9] * r1 + (double)P[10] * r2 + (double)P[11];
    int u = (int)(p0 / pz);
    int v = (int)(p1 / pz);
    u = min(max(u, 0), 1392) >> 3;
    v = min(max(v, 0), 392) >> 3;
    ub[m] = u;
    vb[m] = v;
}

__global__ void scatter_kernel(const int* __restrict__ down, const int* __restrict__ ub,
                               const int* __restrict__ vb, int* __restrict__ grid, int M)
{
    int m = blockIdx.x * 256 + threadIdx.x;
    if (m >= M) return;
    int b = down[4 * m];
    atomicMax(&grid[(b * 175 + ub[m]) * 50 + vb[m]], m);
}

__global__ void nbr2d_kernel(const int* __restrict__ down, const int* __restrict__ ub,
                             const int* __restrict__ vb, const int* __restrict__ grid,
                             int* __restrict__ nb2, int M)
{
    int m = blockIdx.x * 256 + threadIdx.x;
    if (m >= M) return;
    int b = down[4 * m];
    int u = ub[m], v = vb[m];
    #pragma unroll
    for (int j = 0; j < 9; ++j) {
        int uu = u + j / 3 - 1;
        int vv = v + j % 3 - 1;
        int val = -1;
        if (uu >= 0 && uu < 175 && vv >= 0 && vv < 50) val = grid[(b * 175 + uu) * 50 + vv];
        nb2[m * 9 + j] = val;
    }
}

// ---------------- orchestration ----------------
extern "C" void kernel_launch(void* const* d_in, const int* in_sizes, int n_in,
                              void* d_out, int out_size, void* d_ws, size_t ws_size,
                              hipStream_t stream)
{
    const float* feats  = (const float*)d_in[0];
    const float* Wd1    = (const float*)d_in[1];
    const float* Wres   = (const float*)d_in[2];
    const float* Wsub2  = (const float*)d_in[3];
    const float* W2d1   = (const float*)d_in[4];
    const float* W2d2   = (const float*)d_in[5];
    const float* Wsub3  = (const float*)d_in[6];
    const float* Winv4  = (const float*)d_in[7];
    const float* bn32g  = (const float*)d_in[8];
    const float* bn32b  = (const float*)d_in[9];
    const float* bn64g  = (const float*)d_in[10];
    const float* bn64b  = (const float*)d_in[11];
    const float* l2r    = (const float*)d_in[12];
    const float* p2c    = (const float*)d_in[13];
    const int*   down   = (const int*)d_in[14];
    const int*   nbrD   = (const int*)d_in[15];
    const int*   nbrS   = (const int*)d_in[16];
    const int*   nbrI   = (const int*)d_in[17];

    const int N = in_sizes[0] / 64;
    const int M = in_sizes[14] / 4;

    char* ws = (char*)d_ws;
    size_t off = 0;
    auto alloc = [&](size_t bytes) -> void* {
        void* p = ws + off;
        off = (off + bytes + 255) & ~(size_t)255;
        return p;
    };
    float* t0   = (float*)alloc((size_t)M * 32 * 4);
    float* t1   = (float*)alloc((size_t)M * 32 * 4);
    float* t2   = (float*)alloc((size_t)M * 32 * 4);
    int*   ub   = (int*)alloc((size_t)M * 4);
    int*   vb   = (int*)alloc((size_t)M * 4);
    int*   nb2  = (int*)alloc((size_t)M * 9 * 4);
    int*   grid = (int*)alloc((size_t)2 * 175 * 50 * 4);
    float* acc  = (float*)alloc((size_t)9 * ACC_STRIDE * 4);
    float* sc   = (float*)alloc((size_t)9 * 128 * 4);
    float* g0   = (float*)d_out; // N*64 stream computed in the output buffer

    const int accN = 9 * ACC_STRIDE;
    init_zero_kernel<<<(accN + 255) / 256, 256, 0, stream>>>(acc, accN);
    init_m1_kernel<<<(17500 + 255) / 256, 256, 0, stream>>>(grid, 17500);

    const int  gM64  = (M + 63) / 64;   // gconv2: 64 rows/block
    const long tot32 = (long)M * 32;
    const int  gA    = (int)((tot32 + 255) / 256);
    const int  gM    = (M + 255) / 256;

    // stage 1: down1 + res share gathers
    gconv2_kernel<64, 32, 27, true><<<gM64, 256, 0, stream>>>(feats, nbrD, Wd1, Wres, t0, t1, M);
    stats_kernel<32><<<256, 256, 0, stream>>>(t0, M, acc + 0 * ACC_STRIDE);
    stats_kernel<32><<<256, 256, 0, stream>>>(t1, M, acc + 1 * ACC_STRIDE);
    finalize_kernel<32><<<1, 64, 0, stream>>>(acc + 0 * ACC_STRIDE, bn32g + 0 * 32, bn32b + 0 * 32, M, sc + 0 * 128);
    finalize_kernel<32><<<1, 64, 0, stream>>>(acc + 1 * ACC_STRIDE, bn32g + 2 * 32, bn32b + 2 * 32, M, sc + 1 * 128);
    apply_kernel<<<gA, 256, 0, stream>>>(t0, sc + 0 * 128, nullptr, t0, tot32, 31, 1); // d3a
    apply_kernel<<<gA, 256, 0, stream>>>(t1, sc + 1 * 128, nullptr, t1, tot32, 31, 1); // res

    // stage 2: sub2, then d3 = relu(bn(conv)) + res
    gconv2_kernel<32, 32, 27, false><<<gM64, 256, 0, stream>>>(t0, nbrS, Wsub2, nullptr, t2, nullptr, M);
    stats_kernel<32><<<256, 256, 0, stream>>>(t2, M, acc + 2 * ACC_STRIDE);
    finalize_kernel<32><<<1, 64, 0, stream>>>(acc + 2 * ACC_STRIDE, bn32g + 1 * 32, bn32b + 1 * 32, M, sc + 2 * 128);
    apply_kernel<<<gA, 256, 0, stream>>>(t2, sc + 2 * 128, t1, t2, tot32, 31, 1); // t2 = d3

    // 2D neighbor construction
    uv_kernel<<<gM, 256, 0, stream>>>(down, l2r, p2c, M, ub, vb);
    scatter_kernel<<<gM, 256, 0, stream>>>(down, ub, vb, grid, M);
    nbr2d_kernel<<<gM, 256, 0, stream>>>(down, ub, vb, grid, nb2, M);

    // 2d conv 1
    gconv2_kernel<32, 32, 9, false><<<gM64, 256, 0, stream>>>(t2, nb2, W2d1, nullptr, t0, nullptr, M);
    stats_kernel<32><<<256, 256, 0, stream>>>(t0, M, acc + 3 * ACC_STRIDE);
    finalize_kernel<32><<<1, 64, 0, stream>>>(acc + 3 * ACC_STRIDE, bn32g + 3 * 32, bn32b + 3 * 32, M, sc + 3 * 128);
    apply_kernel<<<gA, 256, 0, stream>>>(t0, sc + 3 * 128, nullptr, t0, tot32, 31, 1); // d2a

    // 2d conv 2
    gconv2_kernel<32, 32, 9, false><<<gM64, 256, 0, stream>>>(t0, nb2, W2d2, nullptr, t1, nullptr, M);
    stats_kernel<32><<<256, 256, 0, stream>>>(t1, M, acc + 4 * ACC_STRIDE);
    finalize_kernel<32><<<1, 64, 0, stream>>>(acc + 4 * ACC_STRIDE, bn32g + 4 * 32, bn32b + 4 * 32, M, sc + 4 * 128);
    apply_kernel<<<gA, 256, 0, stream>>>(t1, sc + 4 * 128, nullptr, t1, tot32, 31, 1); // d2b

    // d3 = bn(d3 + d2)
    add_kernel<<<gA, 256, 0, stream>>>(t1, t2, tot32);
    stats_kernel<32><<<256, 256, 0, stream>>>(t1, M, acc + 5 * ACC_STRIDE);
    finalize_kernel<32><<<1, 64, 0, stream>>>(acc + 5 * ACC_STRIDE, bn32g + 5 * 32, bn32b + 5 * 32, M, sc + 5 * 128);
    apply_kernel<<<gA, 256, 0, stream>>>(t1, sc + 5 * 128, nullptr, t1, tot32, 31, 0);

    // sub3
    gconv2_kernel<32, 32, 27, false><<<gM64, 256, 0, stream>>>(t1, nbrS, Wsub3, nullptr, t0, nullptr, M);
    stats_kernel<32><<<256, 256, 0, stream>>>(t0, M, acc + 6 * ACC_STRIDE);
    finalize_kernel<32><<<1, 64, 0, stream>>>(acc + 6 * ACC_STRIDE, bn32g + 6 * 32, bn32b + 6 * 32, M, sc + 6 * 128);
    apply_kernel<<<gA, 256, 0, stream>>>(t0, sc + 6 * 128, nullptr, t0, tot32, 31, 1); // d3f

    // inv4 (N rows) -> directly into d_out
    const int  gN64  = (N + 63) / 64;
    const long tot64 = (long)N * 64;
    const int  gB    = (int)((tot64 + 255) / 256);
    gconv2_kernel<32, 64, 27, false><<<gN64, 256, 0, stream>>>(t0, nbrI, Winv4, nullptr, g0, nullptr, N);
    stats_kernel<64><<<512, 256, 0, stream>>>(g0, N, acc + 7 * ACC_STRIDE);
    finalize_kernel<64><<<1, 64, 0, stream>>>(acc + 7 * ACC_STRIDE, bn64g + 0 * 64, bn64b + 0 * 64, N, sc + 7 * 128);
    apply_kernel<<<gB, 256, 0, stream>>>(g0, sc + 7 * 128, nullptr, g0, tot64, 63, 1); // out2

    // final: bn(out2 + features) -> d_out (in place)
    add_kernel<<<gB, 256, 0, stream>>>(g0, feats, tot64);
    stats_kernel<64><<<512, 256, 0, stream>>>(g0, N, acc + 8 * ACC_STRIDE);
    finalize_kernel<64><<<1, 64, 0, stream>>>(acc + 8 * ACC_STRIDE, bn64g + 1 * 64, bn64b + 1 * 64, N, sc + 8 * 128);
    apply_kernel<<<gB, 256, 0, stream>>>(g0, sc + 8 * 128, nullptr, (float*)d_out, tot64, 63, 0);
}

// Round 7
// 1299.925 us; speedup vs baseline: 2.0547x; 1.5399x over previous
//
#include <hip/hip_runtime.h>

#define NBANK 64
#define ACC_STRIDE (NBANK * 128) // floats per stage accumulator region

// ---------------- init kernels ----------------
__global__ void init_zero_kernel(float* __restrict__ p, int n) {
    int i = blockIdx.x * 256 + threadIdx.x;
    if (i < n) p[i] = 0.f;
}
__global__ void init_m1_kernel(int* __restrict__ p, int n) {
    int i = blockIdx.x * 256 + threadIdx.x;
    if (i < n) p[i] = -1;
}

// ---------------- gather-conv, LDS-tiled register-blocked GEMM ----------------
// C[m][c] = sum_{k,ci} feats[nbr[m,k]][ci] * W[k][ci][c]
// Block: 256 threads, 128-row x COUT tile. KB=32 K-chunk, double-buffered
// shA (transposed [kk][row]) + shW in LDS; NO scalar-mem in the inner loop
// (R6 lesson: s_load + ds_read share lgkmcnt, SMEM is out-of-order -> forced
// coarse waits serialized the K-loop). Thread tile 4 rows x CC cols.
// nbr indices pipelined 2 chunks deep in registers (no LDS copy).
template <int CIN, int COUT, int K, bool DUAL>
__global__ __launch_bounds__(256) void gconv3_kernel(
    const float* __restrict__ feats, const int* __restrict__ nbr,
    const float* __restrict__ W1, const float* __restrict__ W2,
    float* __restrict__ out1, float* __restrict__ out2, int M)
{
    constexpr int TM   = 128;
    constexpr int KB   = 32;
    constexpr int NSUB = CIN / KB;            // ci-chunks per neighbor (1 or 2)
    constexpr int NCH  = K * NSUB;            // total K-chunks
    constexpr int CC   = (COUT == 64) ? 8 : 4; // cols per thread
    constexpr int WPT4 = (KB * COUT) / 1024;  // float4s of W staged per thread (1 or 2)

    __shared__ float shA[2 * KB * TM];                    // 32 KB
    __shared__ float shW1[2 * KB * COUT];                 // 8/16 KB
    __shared__ float shW2[DUAL ? 2 * KB * COUT : 4];      // dual only

    const int tid  = threadIdx.x;
    const int tc   = tid % 8;          // col group -> cols [tc*CC, +CC)
    const int ra   = (tid / 8) * 4;    // compute rows [ra, ra+4)
    const int arow = tid & 127;        // staging row
    const int hh   = tid >> 7;         // staging ci-half (0/1): ci [hh*16, +16)
    const int m0   = blockIdx.x * TM;

    const int  srow  = m0 + arow;
    const bool rowok = (srow < M);

    auto k_of  = [](int ch) { return (NSUB == 2) ? (ch >> 1) : ch; };
    auto cb_of = [](int ch) { return (NSUB == 2) ? ((ch & 1) * KB) : 0; };

    float acc1[4][CC];
    float acc2[DUAL ? 4 : 1][CC];
    #pragma unroll
    for (int r = 0; r < 4; ++r)
        #pragma unroll
        for (int c = 0; c < CC; ++c) acc1[r][c] = 0.f;
    if constexpr (DUAL) {
        #pragma unroll
        for (int r = 0; r < 4; ++r)
            #pragma unroll
            for (int c = 0; c < CC; ++c) acc2[r][c] = 0.f;
    }

    // ---- prologue: stage chunk 0 into buffer 0 ----
    {
        int idx0 = rowok ? nbr[(size_t)srow * K] : -1;  // k=0
        const float4* asrc = (const float4*)(feats + (size_t)max(idx0, 0) * CIN + hh * 16);
        float4 vA[4];
        #pragma unroll
        for (int q = 0; q < 4; ++q) vA[q] = asrc[q];
        #pragma unroll
        for (int q = 0; q < 4; ++q) {
            if (idx0 < 0) vA[q] = make_float4(0.f, 0.f, 0.f, 0.f);
            int kk = hh * 16 + q * 4;
            shA[(kk + 0) * TM + arow] = vA[q].x;
            shA[(kk + 1) * TM + arow] = vA[q].y;
            shA[(kk + 2) * TM + arow] = vA[q].z;
            shA[(kk + 3) * TM + arow] = vA[q].w;
        }
        const float4* w1src = (const float4*)W1;  // chunk 0 base offset = 0
        #pragma unroll
        for (int i = 0; i < WPT4; ++i)
            ((float4*)shW1)[tid * WPT4 + i] = w1src[tid * WPT4 + i];
        if constexpr (DUAL) {
            const float4* w2src = (const float4*)W2;
            #pragma unroll
            for (int i = 0; i < WPT4; ++i)
                ((float4*)shW2)[tid * WPT4 + i] = w2src[tid * WPT4 + i];
        }
    }
    int idx_next = (rowok && NCH > 1) ? nbr[(size_t)srow * K + k_of(1)] : -1;
    __syncthreads();

    // ---- main loop: compute chunk ch, stage chunk ch+1, prefetch nbr ch+2 ----
    for (int ch = 0; ch < NCH; ++ch) {
        const int  p  = ch & 1;
        const bool hn = (ch + 1 < NCH);

        float4 vA[4], wv1[WPT4], wv2[DUAL ? WPT4 : 1];
        if (hn) {
            const int kn  = k_of(ch + 1);
            const int cbn = cb_of(ch + 1);
            const float4* asrc = (const float4*)(feats + (size_t)max(idx_next, 0) * CIN + cbn + hh * 16);
            #pragma unroll
            for (int q = 0; q < 4; ++q) vA[q] = asrc[q];
            const float4* w1src = (const float4*)(W1 + ((size_t)kn * CIN + cbn) * COUT);
            #pragma unroll
            for (int i = 0; i < WPT4; ++i) wv1[i] = w1src[tid * WPT4 + i];
            if constexpr (DUAL) {
                const float4* w2src = (const float4*)(W2 + ((size_t)kn * CIN + cbn) * COUT);
                #pragma unroll
                for (int i = 0; i < WPT4; ++i) wv2[i] = w2src[tid * WPT4 + i];
            }
        }
        int nf = -1;
        if (rowok && ch + 2 < NCH) nf = nbr[(size_t)srow * K + k_of(ch + 2)];

        // compute on buffer p (pure DS + VALU)
        const float* __restrict__ pA  = shA  + p * KB * TM;
        const float* __restrict__ pW1 = shW1 + p * KB * COUT;
        const float* __restrict__ pW2 = DUAL ? (shW2 + p * KB * COUT) : nullptr;
        #pragma unroll 8
        for (int kk = 0; kk < KB; ++kk) {
            float4 a = *(const float4*)&pA[kk * TM + ra];
            float ar[4] = {a.x, a.y, a.z, a.w};
            float4 w1a = *(const float4*)&pW1[kk * COUT + tc * CC];
            float w1r[CC];
            w1r[0] = w1a.x; w1r[1] = w1a.y; w1r[2] = w1a.z; w1r[3] = w1a.w;
            if constexpr (CC == 8) {
                float4 w1b = *(const float4*)&pW1[kk * COUT + tc * CC + 4];
                w1r[4] = w1b.x; w1r[5] = w1b.y; w1r[6] = w1b.z; w1r[7] = w1b.w;
            }
            #pragma unroll
            for (int r = 0; r < 4; ++r)
                #pragma unroll
                for (int c = 0; c < CC; ++c)
                    acc1[r][c] = fmaf(ar[r], w1r[c], acc1[r][c]);
            if constexpr (DUAL) {
                float4 w2a = *(const float4*)&pW2[kk * COUT + tc * CC];
                float w2r[4] = {w2a.x, w2a.y, w2a.z, w2a.w};
                #pragma unroll
                for (int r = 0; r < 4; ++r)
                    #pragma unroll
                    for (int c = 0; c < CC; ++c)
                        acc2[r][c] = fmaf(ar[r], w2r[c], acc2[r][c]);
            }
        }

        // stage chunk ch+1 into buffer p^1
        if (hn) {
            float* dA  = shA  + (p ^ 1) * KB * TM;
            float* dW1 = shW1 + (p ^ 1) * KB * COUT;
            #pragma unroll
            for (int q = 0; q < 4; ++q) {
                if (idx_next < 0) vA[q] = make_float4(0.f, 0.f, 0.f, 0.f);
                int kk = hh * 16 + q * 4;
                dA[(kk + 0) * TM + arow] = vA[q].x;
                dA[(kk + 1) * TM + arow] = vA[q].y;
                dA[(kk + 2) * TM + arow] = vA[q].z;
                dA[(kk + 3) * TM + arow] = vA[q].w;
            }
            #pragma unroll
            for (int i = 0; i < WPT4; ++i)
                ((float4*)dW1)[tid * WPT4 + i] = wv1[i];
            if constexpr (DUAL) {
                float* dW2 = shW2 + (p ^ 1) * KB * COUT;
                #pragma unroll
                for (int i = 0; i < WPT4; ++i)
                    ((float4*)dW2)[tid * WPT4 + i] = wv2[i];
            }
        }
        idx_next = nf;
        __syncthreads();
    }

    // ---- epilogue ----
    #pragma unroll
    for (int r = 0; r < 4; ++r) {
        int m = m0 + ra + r;
        if (m < M) {
            float* d1 = out1 + (size_t)m * COUT + tc * CC;
            *(float4*)d1 = make_float4(acc1[r][0], acc1[r][1], acc1[r][2], acc1[r][3]);
            if constexpr (CC == 8)
                *(float4*)(d1 + 4) = make_float4(acc1[r][4], acc1[r][5], acc1[r][6], acc1[r][7]);
            if constexpr (DUAL) {
                float* d2 = out2 + (size_t)m * COUT + tc * CC;
                *(float4*)d2 = make_float4(acc2[r][0], acc2[r][1], acc2[r][2], acc2[r][3]);
            }
        }
    }
}

// ---------------- BN stats (sum / sumsq per channel, banked atomics) ----------------
template <int C>
__global__ __launch_bounds__(256) void stats_kernel(
    const float* __restrict__ x, int M, float* __restrict__ acc)
{
    constexpr int RPB = 256 / C;
    const int c = threadIdx.x % C;
    const int r = threadIdx.x / C;
    float s = 0.f, s2 = 0.f;
    for (long m = (long)blockIdx.x * RPB + r; m < M; m += (long)gridDim.x * RPB) {
        float v = x[m * C + c];
        s += v;
        s2 += v * v;
    }
    __shared__ float sh[2][256];
    sh[0][threadIdx.x] = s;
    sh[1][threadIdx.x] = s2;
    __syncthreads();
    if (r == 0) {
        #pragma unroll
        for (int j = 1; j < RPB; ++j) {
            s  += sh[0][j * C + c];
            s2 += sh[1][j * C + c];
        }
        float* a = acc + (blockIdx.x % NBANK) * 128;
        atomicAdd(&a[c], s);
        atomicAdd(&a[64 + c], s2);
    }
}

template <int C>
__global__ void finalize_kernel(const float* __restrict__ acc, const float* __restrict__ g,
                                const float* __restrict__ b, int M, float* __restrict__ sc)
{
    int c = threadIdx.x;
    if (c < C) {
        float s = 0.f, s2 = 0.f;
        for (int k = 0; k < NBANK; ++k) {
            s  += acc[k * 128 + c];
            s2 += acc[k * 128 + 64 + c];
        }
        float inv  = 1.f / (float)M;
        float mean = s * inv;
        float var  = s2 * inv - mean * mean;
        float rstd = rsqrtf(var + 1e-3f);
        float scale = g[c] * rstd;
        sc[c]      = scale;
        sc[64 + c] = b[c] - mean * scale;
    }
}

// ---------------- elementwise ----------------
__global__ void apply_kernel(const float* __restrict__ x, const float* __restrict__ sc,
                             const float* __restrict__ addv, float* __restrict__ out,
                             long total, int cmask, int relu)
{
    long i = (long)blockIdx.x * 256 + threadIdx.x;
    if (i >= total) return;
    int c = (int)(i & cmask);
    float v = x[i] * sc[c] + sc[64 + c];
    if (relu) v = fmaxf(v, 0.f);
    if (addv) v += addv[i];
    out[i] = v;
}

__global__ void add_kernel(float* __restrict__ a, const float* __restrict__ b, long total)
{
    long i = (long)blockIdx.x * 256 + threadIdx.x;
    if (i < total) a[i] += b[i];
}

// ---------------- 2D projection / grid / neighbors ----------------
// Verified precision model (R5 PASS): x/y/z in f32 (numpy weak-scalar ops on
// the f32-cast indices), einsums + division in f64 (f32 pts promoted against
// f64-upcast calib). Do not change.
__global__ void uv_kernel(const int* __restrict__ down, const float* __restrict__ l2r,
                          const float* __restrict__ p2, int M,
                          int* __restrict__ ub, int* __restrict__ vb)
{
    int m = blockIdx.x * 256 + threadIdx.x;
    if (m >= M) return;
    int b = down[4 * m];
    float fz = (float)down[4 * m + 1];
    float fy = (float)down[4 * m + 2];
    float fx = (float)down[4 * m + 3];
    const float vs = 0.4f; // f32(0.05*8)
    float x = __fadd_rn(__fmul_rn(fx, vs), 0.2f);
    float y = __fadd_rn(__fmul_rn(fy, vs), -39.79999923706054688f); // f32(-40.0+0.2)
    float z = __fadd_rn(__fmul_rn(fz, vs), -2.79999995231628418f);  // f32(-3.0+0.2)
    double xd = (double)x, yd = (double)y, zd = (double)z;
    const float* L = l2r + b * 12;
    double r0 = (double)L[0] * xd + (double)L[1] * yd + (double)L[2]  * zd + (double)L[3];
    double r1 = (double)L[4] * xd + (double)L[5] * yd + (double)L[6]  * zd + (double)L[7];
    double r2 = (double)L[8] * xd + (double)L[9] * yd + (double)L[10] * zd + (double)L[11];
    const float* P = p2 + b * 12;
    double p0 = (double)P[0] * r0 + (double)P[1] * r1 + (double)P[2]  * r2 + (double)P[3];
    double p1 = (double)P[4] * r0 + (double)P[5] * r1 + (double)P[6]  * r2 + (double)P[7];
    double pz = (double)P[8] * r0 + (double)P[9] * r1 + (double)P[10] * r2 + (double)P[11];
    int u = (int)(p0 / pz);
    int v = (int)(p1 / pz);
    u = min(max(u, 0), 1392) >> 3;
    v = min(max(v, 0), 392) >> 3;
    ub[m] = u;
    vb[m] = v;
}

__global__ void scatter_kernel(const int* __restrict__ down, const int* __restrict__ ub,
                               const int* __restrict__ vb, int* __restrict__ grid, int M)
{
    int m = blockIdx.x * 256 + threadIdx.x;
    if (m >= M) return;
    int b = down[4 * m];
    atomicMax(&grid[(b * 175 + ub[m]) * 50 + vb[m]], m);
}

__global__ void nbr2d_kernel(const int* __restrict__ down, const int* __restrict__ ub,
                             const int* __restrict__ vb, const int* __restrict__ grid,
                             int* __restrict__ nb2, int M)
{
    int m = blockIdx.x * 256 + threadIdx.x;
    if (m >= M) return;
    int b = down[4 * m];
    int u = ub[m], v = vb[m];
    #pragma unroll
    for (int j = 0; j < 9; ++j) {
        int uu = u + j / 3 - 1;
        int vv = v + j % 3 - 1;
        int val = -1;
        if (uu >= 0 && uu < 175 && vv >= 0 && vv < 50) val = grid[(b * 175 + uu) * 50 + vv];
        nb2[m * 9 + j] = val;
    }
}

// ---------------- orchestration ----------------
extern "C" void kernel_launch(void* const* d_in, const int* in_sizes, int n_in,
                              void* d_out, int out_size, void* d_ws, size_t ws_size,
                              hipStream_t stream)
{
    const float* feats  = (const float*)d_in[0];
    const float* Wd1    = (const float*)d_in[1];
    const float* Wres   = (const float*)d_in[2];
    const float* Wsub2  = (const float*)d_in[3];
    const float* W2d1   = (const float*)d_in[4];
    const float* W2d2   = (const float*)d_in[5];
    const float* Wsub3  = (const float*)d_in[6];
    const float* Winv4  = (const float*)d_in[7];
    const float* bn32g  = (const float*)d_in[8];
    const float* bn32b  = (const float*)d_in[9];
    const float* bn64g  = (const float*)d_in[10];
    const float* bn64b  = (const float*)d_in[11];
    const float* l2r    = (const float*)d_in[12];
    const float* p2c    = (const float*)d_in[13];
    const int*   down   = (const int*)d_in[14];
    const int*   nbrD   = (const int*)d_in[15];
    const int*   nbrS   = (const int*)d_in[16];
    const int*   nbrI   = (const int*)d_in[17];

    const int N = in_sizes[0] / 64;
    const int M = in_sizes[14] / 4;

    char* ws = (char*)d_ws;
    size_t off = 0;
    auto alloc = [&](size_t bytes) -> void* {
        void* p = ws + off;
        off = (off + bytes + 255) & ~(size_t)255;
        return p;
    };
    float* t0   = (float*)alloc((size_t)M * 32 * 4);
    float* t1   = (float*)alloc((size_t)M * 32 * 4);
    float* t2   = (float*)alloc((size_t)M * 32 * 4);
    int*   ub   = (int*)alloc((size_t)M * 4);
    int*   vb   = (int*)alloc((size_t)M * 4);
    int*   nb2  = (int*)alloc((size_t)M * 9 * 4);
    int*   grid = (int*)alloc((size_t)2 * 175 * 50 * 4);
    float* acc  = (float*)alloc((size_t)9 * ACC_STRIDE * 4);
    float* sc   = (float*)alloc((size_t)9 * 128 * 4);
    float* g0   = (float*)d_out; // N*64 stream computed in the output buffer

    const int accN = 9 * ACC_STRIDE;
    init_zero_kernel<<<(accN + 255) / 256, 256, 0, stream>>>(acc, accN);
    init_m1_kernel<<<(17500 + 255) / 256, 256, 0, stream>>>(grid, 17500);

    const int  gT   = (M + 127) / 128;   // gconv3: 128 rows/block
    const long tot32 = (long)M * 32;
    const int  gA    = (int)((tot32 + 255) / 256);
    const int  gM    = (M + 255) / 256;

    // stage 1: down1 + res share gathers
    gconv3_kernel<64, 32, 27, true><<<gT, 256, 0, stream>>>(feats, nbrD, Wd1, Wres, t0, t1, M);
    stats_kernel<32><<<256, 256, 0, stream>>>(t0, M, acc + 0 * ACC_STRIDE);
    stats_kernel<32><<<256, 256, 0, stream>>>(t1, M, acc + 1 * ACC_STRIDE);
    finalize_kernel<32><<<1, 64, 0, stream>>>(acc + 0 * ACC_STRIDE, bn32g + 0 * 32, bn32b + 0 * 32, M, sc + 0 * 128);
    finalize_kernel<32><<<1, 64, 0, stream>>>(acc + 1 * ACC_STRIDE, bn32g + 2 * 32, bn32b + 2 * 32, M, sc + 1 * 128);
    apply_kernel<<<gA, 256, 0, stream>>>(t0, sc + 0 * 128, nullptr, t0, tot32, 31, 1); // d3a
    apply_kernel<<<gA, 256, 0, stream>>>(t1, sc + 1 * 128, nullptr, t1, tot32, 31, 1); // res

    // stage 2: sub2, then d3 = relu(bn(conv)) + res
    gconv3_kernel<32, 32, 27, false><<<gT, 256, 0, stream>>>(t0, nbrS, Wsub2, nullptr, t2, nullptr, M);
    stats_kernel<32><<<256, 256, 0, stream>>>(t2, M, acc + 2 * ACC_STRIDE);
    finalize_kernel<32><<<1, 64, 0, stream>>>(acc + 2 * ACC_STRIDE, bn32g + 1 * 32, bn32b + 1 * 32, M, sc + 2 * 128);
    apply_kernel<<<gA, 256, 0, stream>>>(t2, sc + 2 * 128, t1, t2, tot32, 31, 1); // t2 = d3

    // 2D neighbor construction
    uv_kernel<<<gM, 256, 0, stream>>>(down, l2r, p2c, M, ub, vb);
    scatter_kernel<<<gM, 256, 0, stream>>>(down, ub, vb, grid, M);
    nbr2d_kernel<<<gM, 256, 0, stream>>>(down, ub, vb, grid, nb2, M);

    // 2d conv 1
    gconv3_kernel<32, 32, 9, false><<<gT, 256, 0, stream>>>(t2, nb2, W2d1, nullptr, t0, nullptr, M);
    stats_kernel<32><<<256, 256, 0, stream>>>(t0, M, acc + 3 * ACC_STRIDE);
    finalize_kernel<32><<<1, 64, 0, stream>>>(acc + 3 * ACC_STRIDE, bn32g + 3 * 32, bn32b + 3 * 32, M, sc + 3 * 128);
    apply_kernel<<<gA, 256, 0, stream>>>(t0, sc + 3 * 128, nullptr, t0, tot32, 31, 1); // d2a

    // 2d conv 2
    gconv3_kernel<32, 32, 9, false><<<gT, 256, 0, stream>>>(t0, nb2, W2d2, nullptr, t1, nullptr, M);
    stats_kernel<32><<<256, 256, 0, stream>>>(t1, M, acc + 4 * ACC_STRIDE);
    finalize_kernel<32><<<1, 64, 0, stream>>>(acc + 4 * ACC_STRIDE, bn32g + 4 * 32, bn32b + 4 * 32, M, sc + 4 * 128);
    apply_kernel<<<gA, 256, 0, stream>>>(t1, sc + 4 * 128, nullptr, t1, tot32, 31, 1); // d2b

    // d3 = bn(d3 + d2)
    add_kernel<<<gA, 256, 0, stream>>>(t1, t2, tot32);
    stats_kernel<32><<<256, 256, 0, stream>>>(t1, M, acc + 5 * ACC_STRIDE);
    finalize_kernel<32><<<1, 64, 0, stream>>>(acc + 5 * ACC_STRIDE, bn32g + 5 * 32, bn32b + 5 * 32, M, sc + 5 * 128);
    apply_kernel<<<gA, 256, 0, stream>>>(t1, sc + 5 * 128, nullptr, t1, tot32, 31, 0);

    // sub3
    gconv3_kernel<32, 32, 27, false><<<gT, 256, 0, stream>>>(t1, nbrS, Wsub3, nullptr, t0, nullptr, M);
    stats_kernel<32><<<256, 256, 0, stream>>>(t0, M, acc + 6 * ACC_STRIDE);
    finalize_kernel<32><<<1, 64, 0, stream>>>(acc + 6 * ACC_STRIDE, bn32g + 6 * 32, bn32b + 6 * 32, M, sc + 6 * 128);
    apply_kernel<<<gA, 256, 0, stream>>>(t0, sc + 6 * 128, nullptr, t0, tot32, 31, 1); // d3f

    // inv4 (N rows) -> directly into d_out
    const int  gTN   = (N + 127) / 128;
    const long tot64 = (long)N * 64;
    const int  gB    = (int)((tot64 + 255) / 256);
    gconv3_kernel<32, 64, 27, false><<<gTN, 256, 0, stream>>>(t0, nbrI, Winv4, nullptr, g0, nullptr, N);
    stats_kernel<64><<<512, 256, 0, stream>>>(g0, N, acc + 7 * ACC_STRIDE);
    finalize_kernel<64><<<1, 64, 0, stream>>>(acc + 7 * ACC_STRIDE, bn64g + 0 * 64, bn64b + 0 * 64, N, sc + 7 * 128);
    apply_kernel<<<gB, 256, 0, stream>>>(g0, sc + 7 * 128, nullptr, g0, tot64, 63, 1); // out2

    // final: bn(out2 + features) -> d_out (in place)
    add_kernel<<<gB, 256, 0, stream>>>(g0, feats, tot64);
    stats_kernel<64><<<512, 256, 0, stream>>>(g0, N, acc + 8 * ACC_STRIDE);
    finalize_kernel<64><<<1, 64, 0, stream>>>(acc + 8 * ACC_STRIDE, bn64g + 1 * 64, bn64b + 1 * 64, N, sc + 8 * 128);
    apply_kernel<<<gB, 256, 0, stream>>>(g0, sc + 8 * 128, nullptr, (float*)d_out, tot64, 63, 0);
}